// Round 14
// baseline (263.774 us; speedup 1.0000x reference)
//
#include <hip/hip_runtime.h>
#include <cstddef>

#define N_NODES 100000
#define N_EDGES 1600000
#define D 128
#define NB 782          // ceil(N_NODES/128) buckets of 128 dst nodes
#define CAP 3072        // csr/bucket window capacity (mean 2046, sd ~45)
#define NBLK 1000       // scatter blocks (CHUNK*NBLK == N_EDGES)
#define CHUNK 1600      // edges per scatter block
#define OROW 784        // offs row stride (NB+1 entries, padded)
#define WTOT (6 * 16384 + 8192)  // 106496 weight elements
#define XBLK 6250       // x-convert blocks
#define WBLK ((WTOT + 255) / 256)

typedef unsigned int u32;
typedef unsigned long long u64;
typedef float f32x4 __attribute__((ext_vector_type(4)));
typedef _Float16 f16x8 __attribute__((ext_vector_type(8)));

__device__ inline f16x8 mk16(u64 a, u64 b) {
  union { u64 q[2]; f16x8 v; } u;
  u.q[0] = a; u.q[1] = b;
  return u.v;
}

// accumulate 8 u8 lanes * scale into a[8]
__device__ inline void acc8(float* a, u32 dx, u32 dy, float c) {
  a[0] += (float)(dx & 0xFFu) * c;
  a[1] += (float)((dx >> 8) & 0xFFu) * c;
  a[2] += (float)((dx >> 16) & 0xFFu) * c;
  a[3] += (float)(dx >> 24) * c;
  a[4] += (float)(dy & 0xFFu) * c;
  a[5] += (float)((dy >> 8) & 0xFFu) * c;
  a[6] += (float)((dy >> 16) & 0xFFu) * c;
  a[7] += (float)(dy >> 24) * c;
}

// dequant 4 u8 -> 4 f16 (packed u64): val = q*c + n
__device__ inline u64 dq4(u32 w, float c, float n) {
  float f0 = fmaf((float)(w & 0xFFu), c, n);
  float f1 = fmaf((float)((w >> 8) & 0xFFu), c, n);
  float f2 = fmaf((float)((w >> 16) & 0xFFu), c, n);
  float f3 = fmaf((float)(w >> 24), c, n);
  auto lo = __builtin_amdgcn_cvt_pkrtz(f0, f1);  // __fp16 ext_vector(2)
  auto hi = __builtin_amdgcn_cvt_pkrtz(f2, f3);
  return (u64)__builtin_bit_cast(u32, lo) | ((u64)__builtin_bit_cast(u32, hi) << 32);
}

// ---------------- prep + scatter (merged: independent jobs, one launch) -------
// blocks [0,NBLK): edge scatter into private segments (R11-proven).
// blocks [NBLK, NBLK+XBLK): x -> biased-u8 + per-row scale.
// blocks [NBLK+XBLK, ...): weights -> transposed f16.

__global__ __launch_bounds__(256) void k_prep(
    const float* __restrict__ x,
    unsigned char* __restrict__ x8, float* __restrict__ sx,
    const float* __restrict__ w0, const float* __restrict__ w1, const float* __restrict__ w2,
    const float* __restrict__ w3, const float* __restrict__ w4, const float* __restrict__ w5,
    const float* __restrict__ w6, unsigned short* __restrict__ wt16,
    const int* __restrict__ src, const int* __restrict__ dst,
    u32* __restrict__ binned, u32* __restrict__ offs) {
  __shared__ int cnt[NB];
  __shared__ int lbase[NB + 1];
  __shared__ int wsum[256];
  __shared__ u32 stage[CHUNK];
  const int bid = blockIdx.x;
  const int tid = threadIdx.x;

  if (bid < NBLK) {
    // ---- scatter ----
    for (int i = tid; i < NB; i += 256) cnt[i] = 0;
    __syncthreads();
    const int e0 = bid * CHUNK;
    for (int e = e0 + tid; e < e0 + CHUNK; e += 256)
      atomicAdd(&cnt[dst[e] >> 7], 1);
    __syncthreads();
    int c[4], s = 0;
#pragma unroll
    for (int j = 0; j < 4; j++) {
      int i = tid * 4 + j;
      c[j] = (i < NB) ? cnt[i] : 0;
      s += c[j];
    }
    wsum[tid] = s;
    __syncthreads();
    for (int off = 1; off < 256; off <<= 1) {
      int t = (tid >= off) ? wsum[tid - off] : 0;
      __syncthreads();
      wsum[tid] += t;
      __syncthreads();
    }
    int run = wsum[tid] - s;
#pragma unroll
    for (int j = 0; j < 4; j++) {
      int i = tid * 4 + j;
      if (i < NB) { lbase[i] = run; run += c[j]; }
    }
    if (tid == 0) lbase[NB] = CHUNK;
    __syncthreads();
    for (int i = tid; i < NB; i += 256) cnt[i] = 0;
    __syncthreads();
    for (int e = e0 + tid; e < e0 + CHUNK; e += 256) {
      int d = dst[e];
      int bkt = d >> 7;
      int l = atomicAdd(&cnt[bkt], 1);
      stage[lbase[bkt] + l] = ((u32)(d & 127) << 17) | (u32)src[e];
    }
    u32* orow = offs + (size_t)bid * OROW;
    for (int i = tid; i <= NB; i += 256) orow[i] = (u32)lbase[i];
    __syncthreads();
    u32* bseg = binned + (size_t)bid * CHUNK;
    for (int i = tid; i < CHUNK / 4; i += 256)
      *(uint4*)(bseg + i * 4) = *(const uint4*)(stage + i * 4);
    return;
  }
  if (bid < NBLK + XBLK) {
    // ---- x convert ----
    int row = (bid - NBLK) * 16 + (tid >> 4);   // 6250*16 = 100000 exact
    int sub = tid & 15;
    const float* xr = x + (size_t)row * D + sub * 8;
    float4 v0 = *(const float4*)xr;
    float4 v1 = *(const float4*)(xr + 4);
    float vs[8] = {v0.x, v0.y, v0.z, v0.w, v1.x, v1.y, v1.z, v1.w};
    float m = 0.f;
#pragma unroll
    for (int j = 0; j < 8; j++) m = fmaxf(m, fabsf(vs[j]));
#pragma unroll
    for (int off = 1; off < 16; off <<= 1) m = fmaxf(m, __shfl_xor(m, off));
    m = fmaxf(m, 1e-8f);
    float inv = 127.0f / m;
    u64 pk = 0;
#pragma unroll
    for (int j = 0; j < 8; j++) {
      int qi = (int)rintf(vs[j] * inv) + 128;  // [1,255]
      pk |= (u64)(u32)(qi & 255) << (8 * j);
    }
    *(u64*)(x8 + (size_t)row * D + sub * 8) = pk;
    if (sub == 0) sx[row] = m / 127.0f;
    return;
  }
  // ---- weights ----
  int i = (bid - NBLK - XBLK) * 256 + tid;
  if (i >= WTOT) return;
  float v;
  if (i < 6 * 16384) {
    int m = i >> 14;  // 0..5 -> Wl0,Wr0,Wl1,Wr1,Wl2,Wr2
    int j = i & 16383;
    int c = j >> 7, k = j & 127;
    const float* w = (m == 0) ? w0 : (m == 1) ? w1 : (m == 2) ? w2
                   : (m == 3) ? w3 : (m == 4) ? w4 : w5;
    v = w[k * 128 + c];
  } else {
    int j = i - 6 * 16384;
    int c = j >> 7, k = j & 127;
    v = w6[k * 64 + c];
  }
  _Float16 h = (_Float16)v;
  wt16[i] = __builtin_bit_cast(unsigned short, h);
}

// ---------------- graph build, stage 2: per-bucket gather + CSR ----------------

__global__ __launch_bounds__(256) void k_build(const u32* __restrict__ binned,
                                               const u32* __restrict__ offs,
                                               int* __restrict__ row_start,
                                               int* __restrict__ row_end,
                                               float* __restrict__ inv_deg,
                                               int* __restrict__ csr_src) {
  __shared__ u32 stage[CAP];
  __shared__ int deg[128], sc[128], cur[128];
  __shared__ int fill;
  const int b = blockIdx.x;
  const int tid = threadIdx.x;
  if (tid == 0) fill = 0;
  if (tid < 128) deg[tid] = 0;
  __syncthreads();
  for (int k = tid; k < NBLK; k += 256) {
    const u32* orow = offs + (size_t)k * OROW;
    int o0 = (int)orow[b], o1 = (int)orow[b + 1];
    int n = o1 - o0;
    if (n > 0) {
      int p = atomicAdd(&fill, n);
      const u32* q = binned + (size_t)k * CHUNK + o0;
      for (int j = 0; j < n; ++j) stage[p + j] = q[j];
    }
  }
  __syncthreads();
  const int total = fill;
  for (int e = tid; e < total; e += 256)
    atomicAdd(&deg[stage[e] >> 17], 1);
  __syncthreads();
  int dv = (tid < 128) ? deg[tid] : 0;
  if (tid < 128) sc[tid] = dv;
  __syncthreads();
  for (int off = 1; off < 128; off <<= 1) {
    int t = (tid >= off && tid < 128) ? sc[tid - off] : 0;
    __syncthreads();
    if (tid < 128) sc[tid] += t;
    __syncthreads();
  }
  const int cbase = b * CAP;
  if (tid < 128) {
    int excl = sc[tid] - dv;
    cur[tid] = excl;
    int node = (b << 7) + tid;
    if (node < N_NODES) {
      row_start[node] = cbase + excl;
      row_end[node] = cbase + excl + dv;
      inv_deg[node] = 1.0f / fmaxf((float)dv, 1.0f);
    }
  }
  __syncthreads();
  for (int e = tid; e < total; e += 256) {
    u32 w = stage[e];
    int dl = w >> 17;
    int pos = cbase + atomicAdd(&cur[dl], 1);
    csr_src[pos] = (int)(w & 0x1FFFFu);
  }
}

// ---------------- aggregation: 8 lanes/node, 16B/lane, cooperative idx fetch ----
// Per 8-lane subgroup: lane sub loads csr_src[p+sub] (coalesced) + qs[idx]
// (gather); __shfl(.,j,8) broadcasts -> 10 VMEM instrs per 64 neighbors
// (vs ~48 in the 16-lane shape). BIN/BOUT as before.

template <bool BIN, bool BOUT>
__global__ __launch_bounds__(256) void k_agg(const unsigned char* __restrict__ q8,
                                             const float* __restrict__ qs,
                                             const int* __restrict__ row_start,
                                             const int* __restrict__ row_end,
                                             const float* __restrict__ inv_deg,
                                             const int* __restrict__ csr_src,
                                             unsigned char* __restrict__ out8,
                                             float* __restrict__ sout) {
  int node = blockIdx.x * 32 + (threadIdx.x >> 3);
  if (node >= N_NODES) return;
  int sub = threadIdx.x & 7;
  int p0 = row_start[node], p1 = row_end[node];
  float a[16];
#pragma unroll
  for (int j = 0; j < 16; j++) a[j] = 0.f;
  float ssum = 0.f;
  int p = p0;
  for (; p + 8 <= p1; p += 8) {
    int myidx = csr_src[p + sub];   // coalesced across subgroup
    float myc = qs[myidx];          // per-lane gather
#pragma unroll
    for (int j = 0; j < 8; j++) {
      int s = __shfl(myidx, j, 8);
      float c = __shfl(myc, j, 8);
      uint4 d = *(const uint4*)(q8 + (size_t)s * D + sub * 16);
      acc8(a, d.x, d.y, c);
      acc8(a + 8, d.z, d.w, c);
      if (BIN) ssum += c;
    }
  }
  for (; p < p1; ++p) {
    int s = csr_src[p];
    float c = qs[s];
    uint4 d = *(const uint4*)(q8 + (size_t)s * D + sub * 16);
    acc8(a, d.x, d.y, c);
    acc8(a + 8, d.z, d.w, c);
    if (BIN) ssum += c;
  }
  float scl = inv_deg[node];
  float v[16];
#pragma unroll
  for (int j = 0; j < 16; j++) {
    float t = a[j];
    if (BIN) t -= 128.0f * ssum;
    v[j] = t * scl;
  }
  float m = 0.f;
#pragma unroll
  for (int j = 0; j < 16; j++) m = fmaxf(m, BOUT ? fabsf(v[j]) : v[j]);
#pragma unroll
  for (int off = 1; off < 8; off <<= 1) m = fmaxf(m, __shfl_xor(m, off));
  m = fmaxf(m, 1e-8f);
  u64 pk0 = 0, pk1 = 0;
  if (BOUT) {
    float inv = 127.0f / m;
#pragma unroll
    for (int j = 0; j < 8; j++) {
      int q0 = (int)rintf(v[j] * inv) + 128;
      int q1 = (int)rintf(v[j + 8] * inv) + 128;
      pk0 |= (u64)(u32)(q0 & 255) << (8 * j);
      pk1 |= (u64)(u32)(q1 & 255) << (8 * j);
    }
  } else {
    float inv = 255.0f / m;
#pragma unroll
    for (int j = 0; j < 8; j++) {
      u32 q0 = (u32)(v[j] * inv + 0.5f);
      u32 q1 = (u32)(v[j + 8] * inv + 0.5f);
      pk0 |= (u64)(q0 & 255) << (8 * j);
      pk1 |= (u64)(q1 & 255) << (8 * j);
    }
  }
  union { u64 q[2]; uint4 u; } st;
  st.q[0] = pk0; st.q[1] = pk1;
  *(uint4*)(out8 + (size_t)node * D + sub * 16) = st.u;
  if (sub == 0) sout[node] = m / (BOUT ? 127.0f : 255.0f);
}

// ---------------- MFMA GEMM (layers 0,1): all-u8 operands, dequant in staging ----

template <bool B0, bool B1>
__global__ __launch_bounds__(256) void k_gemm(
    const unsigned char* __restrict__ in0, const float* __restrict__ s0,
    const unsigned char* __restrict__ in1, const float* __restrict__ s1,
    const unsigned short* __restrict__ wt, const float* __restrict__ bias,
    unsigned char* __restrict__ h8out, float* __restrict__ shout) {
  __shared__ u64 sI[128][9];
  __shared__ u64 sW[128][9];
  __shared__ u32 rmaxb[128];
  __shared__ unsigned char h8t[128 * 144];  // stride 144 (16B-aligned rows)

  const int tid = threadIdx.x;
  const int row0 = blockIdx.x * 128;
  const int lane = tid & 63;
  const int w = tid >> 6;
  const int wr = w >> 1, wc = w & 1;
  const int lrow = lane & 15, kb = lane >> 4;
  const int sr = tid >> 2, sq = tid & 3;

  f32x4 acc[4][4];
#pragma unroll
  for (int i = 0; i < 4; i++)
#pragma unroll
    for (int j = 0; j < 4; j++) acc[i][j] = (f32x4){0.f, 0.f, 0.f, 0.f};

  uint2 rd[2]; float rc[2];
  u64 rW[2][2];

  auto loadA = [&](int ch) {
    const unsigned char* inP = (ch >= 4) ? in1 : in0;
    const float* sP = (ch >= 4) ? s1 : s0;
    const int kc = (ch & 3) * 32;
#pragma unroll
    for (int it = 0; it < 2; ++it) {
      int g = row0 + sr + it * 64;
      uint2 d = make_uint2(0, 0);
      float c = 0.f;
      if (g < N_NODES) {
        d = *(const uint2*)(inP + (size_t)g * D + kc + sq * 8);
        c = sP[g];
      }
      rd[it] = d; rc[it] = c;
    }
  };
  auto loadW = [&](int ch) {
    const int s = ch >> 2;
    const int kc = (ch & 3) * 32;
    const unsigned short* wP = wt + (size_t)s * 16384;
#pragma unroll
    for (int it = 0; it < 2; ++it) {
      int c = sr + it * 64;
      const u64* pp = (const u64*)(wP + (size_t)c * D + kc + sq * 8);
      rW[it][0] = pp[0]; rW[it][1] = pp[1];
    }
  };

  loadA(0); loadW(0);
#pragma unroll
  for (int ch = 0; ch < 8; ++ch) {
    const bool biased = (ch < 4) ? B0 : B1;
    __syncthreads();
#pragma unroll
    for (int it = 0; it < 2; ++it) {
      int r = sr + it * 64;
      float c = rc[it];
      float n = biased ? -128.0f * c : 0.0f;
      sI[r][sq * 2] = dq4(rd[it].x, c, n);
      sI[r][sq * 2 + 1] = dq4(rd[it].y, c, n);
      sW[r][sq * 2] = rW[it][0]; sW[r][sq * 2 + 1] = rW[it][1];
    }
    __syncthreads();
    if (ch < 7) { loadA(ch + 1); loadW(ch + 1); }

    f16x8 fA[4], fB[4];
#pragma unroll
    for (int rt = 0; rt < 4; ++rt) {
      int rr = wr * 64 + rt * 16 + lrow;
      fA[rt] = mk16(sI[rr][kb * 2], sI[rr][kb * 2 + 1]);
    }
#pragma unroll
    for (int ct = 0; ct < 4; ++ct) {
      int cc = wc * 64 + ct * 16 + lrow;
      fB[ct] = mk16(sW[cc][kb * 2], sW[cc][kb * 2 + 1]);
    }
#pragma unroll
    for (int ct = 0; ct < 4; ++ct)
#pragma unroll
      for (int rt = 0; rt < 4; ++rt)
        acc[rt][ct] = __builtin_amdgcn_mfma_f32_16x16x32_f16(fA[rt], fB[ct], acc[rt][ct], 0, 0, 0);
  }

  // ---- epilogue: bias+relu, rowmax, u8 quantize ----
  if (tid < 128) rmaxb[tid] = 0;
  float bv[4];
#pragma unroll
  for (int ct = 0; ct < 4; ++ct) bv[ct] = bias[wc * 64 + ct * 16 + lrow];
#pragma unroll
  for (int ct = 0; ct < 4; ++ct)
#pragma unroll
    for (int rt = 0; rt < 4; ++rt)
#pragma unroll
      for (int r = 0; r < 4; ++r)
        acc[rt][ct][r] = fmaxf(acc[rt][ct][r] + bv[ct], 0.f);
  __syncthreads();  // rmaxb init visible
#pragma unroll
  for (int rt = 0; rt < 4; ++rt) {
#pragma unroll
    for (int r = 0; r < 4; ++r) {
      float m = fmaxf(fmaxf(acc[rt][0][r], acc[rt][1][r]),
                      fmaxf(acc[rt][2][r], acc[rt][3][r]));
      m = fmaxf(m, __shfl_xor(m, 1));
      m = fmaxf(m, __shfl_xor(m, 2));
      m = fmaxf(m, __shfl_xor(m, 4));
      m = fmaxf(m, __shfl_xor(m, 8));
      if (lrow == 0)
        atomicMax(&rmaxb[wr * 64 + rt * 16 + kb * 4 + r], __float_as_uint(m));
    }
  }
  __syncthreads();
#pragma unroll
  for (int rt = 0; rt < 4; ++rt) {
#pragma unroll
    for (int r = 0; r < 4; ++r) {
      int row = wr * 64 + rt * 16 + kb * 4 + r;
      float rm = fmaxf(__uint_as_float(rmaxb[row]), 1e-8f);
      float inv = 255.0f / rm;
#pragma unroll
      for (int ct = 0; ct < 4; ++ct) {
        u32 q = (u32)(acc[rt][ct][r] * inv + 0.5f);
        h8t[row * 144 + wc * 64 + ct * 16 + lrow] = (unsigned char)q;
      }
    }
  }
  __syncthreads();
  for (int idx = tid; idx < 128 * 8; idx += 256) {
    int row = idx >> 3, qq = idx & 7;
    int g = row0 + row;
    if (g < N_NODES)
      *(uint4*)(h8out + (size_t)g * D + qq * 16) =
          *(const uint4*)(h8t + row * 144 + qq * 16);
  }
  if (tid < 128 && row0 + tid < N_NODES)
    shout[row0 + tid] = fmaxf(__uint_as_float(rmaxb[tid]), 1e-8f) / 255.0f;
}

// ---------------- layer-2 GEMM + fused final projection (u8 operands) ----------

template <bool B0, bool B1>
__global__ __launch_bounds__(256) void k_gemm2(
    const unsigned char* __restrict__ in0, const float* __restrict__ s0,
    const unsigned char* __restrict__ in1, const float* __restrict__ s1,
    const unsigned short* __restrict__ wt, const float* __restrict__ bias,
    const unsigned short* __restrict__ w2, const float* __restrict__ b2,
    float* __restrict__ outp) {
  __shared__ __align__(16) char smem[128 * 33 * 8 + 2 * 128 * 9 * 8];
  u64 (*sH3)[33] = (u64(*)[33])smem;
  u64 (*sI)[9] = (u64(*)[9])(smem + 128 * 33 * 8);
  u64 (*sW)[9] = (u64(*)[9])(smem + 128 * 33 * 8 + 128 * 9 * 8);
  u64 (*sW2)[33] = (u64(*)[33])(smem + 128 * 33 * 8);  // alias of sI/sW, phase B only

  const int tid = threadIdx.x;
  const int row0 = blockIdx.x * 128;
  const int lane = tid & 63;
  const int w = tid >> 6;
  const int wr = w >> 1, wc = w & 1;
  const int lrow = lane & 15, kb = lane >> 4;
  const int sr = tid >> 2, sq = tid & 3;

  f32x4 acc[4][4];
#pragma unroll
  for (int i = 0; i < 4; i++)
#pragma unroll
    for (int j = 0; j < 4; j++) acc[i][j] = (f32x4){0.f, 0.f, 0.f, 0.f};

  uint2 rd[2]; float rc[2];
  u64 rW[2][2];

  auto loadA = [&](int ch) {
    const unsigned char* inP = (ch >= 4) ? in1 : in0;
    const float* sP = (ch >= 4) ? s1 : s0;
    const int kc = (ch & 3) * 32;
#pragma unroll
    for (int it = 0; it < 2; ++it) {
      int g = row0 + sr + it * 64;
      uint2 d = make_uint2(0, 0);
      float c = 0.f;
      if (g < N_NODES) {
        d = *(const uint2*)(inP + (size_t)g * D + kc + sq * 8);
        c = sP[g];
      }
      rd[it] = d; rc[it] = c;
    }
  };
  auto loadW = [&](int ch) {
    const int s = ch >> 2;
    const int kc = (ch & 3) * 32;
    const unsigned short* wP = wt + (size_t)s * 16384;
#pragma unroll
    for (int it = 0; it < 2; ++it) {
      int c = sr + it * 64;
      const u64* pp = (const u64*)(wP + (size_t)c * D + kc + sq * 8);
      rW[it][0] = pp[0]; rW[it][1] = pp[1];
    }
  };

  loadA(0); loadW(0);
#pragma unroll
  for (int ch = 0; ch < 8; ++ch) {
    const bool biased = (ch < 4) ? B0 : B1;
    __syncthreads();
#pragma unroll
    for (int it = 0; it < 2; ++it) {
      int r = sr + it * 64;
      float c = rc[it];
      float n = biased ? -128.0f * c : 0.0f;
      sI[r][sq * 2] = dq4(rd[it].x, c, n);
      sI[r][sq * 2 + 1] = dq4(rd[it].y, c, n);
      sW[r][sq * 2] = rW[it][0]; sW[r][sq * 2 + 1] = rW[it][1];
    }
    __syncthreads();
    if (ch < 7) { loadA(ch + 1); loadW(ch + 1); }

    f16x8 fA[4], fB[4];
#pragma unroll
    for (int rt = 0; rt < 4; ++rt) {
      int rr = wr * 64 + rt * 16 + lrow;
      fA[rt] = mk16(sI[rr][kb * 2], sI[rr][kb * 2 + 1]);
    }
#pragma unroll
    for (int ct = 0; ct < 4; ++ct) {
      int cc = wc * 64 + ct * 16 + lrow;
      fB[ct] = mk16(sW[cc][kb * 2], sW[cc][kb * 2 + 1]);
    }
#pragma unroll
    for (int ct = 0; ct < 4; ++ct)
#pragma unroll
      for (int rt = 0; rt < 4; ++rt)
        acc[rt][ct] = __builtin_amdgcn_mfma_f32_16x16x32_f16(fA[rt], fB[ct], acc[rt][ct], 0, 0, 0);
  }

  // ---- phase B ----
#pragma unroll
  for (int ct = 0; ct < 4; ++ct) {
    int col = wc * 64 + ct * 16 + lrow;
    float bv = bias[col];
#pragma unroll
    for (int rt = 0; rt < 4; ++rt) {
      int rbase = wr * 64 + rt * 16 + kb * 4;
#pragma unroll
      for (int r = 0; r < 4; ++r) {
        float v = fmaxf(acc[rt][ct][r] + bv, 0.f);
        _Float16 hv = (_Float16)v;
        ((unsigned short*)(&sH3[rbase + r][0]))[col] = __builtin_bit_cast(unsigned short, hv);
      }
    }
  }
  __syncthreads();  // phase-A LDS reads retired; h3 visible -> safe to alias sI/sW
  for (int idx = tid; idx < 64 * 32; idx += 256) {
    int c = idx >> 5, j = idx & 31;
    sW2[c][j] = ((const u64*)(w2 + (size_t)c * D))[j];
  }
  __syncthreads();

  f32x4 acc2[4][2];
#pragma unroll
  for (int i = 0; i < 4; i++)
#pragma unroll
    for (int j = 0; j < 2; j++) acc2[i][j] = (f32x4){0.f, 0.f, 0.f, 0.f};

#pragma unroll
  for (int kc2 = 0; kc2 < 4; ++kc2) {
    f16x8 fA[4], fB[2];
#pragma unroll
    for (int rt = 0; rt < 4; ++rt) {
      int rr = wr * 64 + rt * 16 + lrow;
      fA[rt] = mk16(sH3[rr][kc2 * 8 + kb * 2], sH3[rr][kc2 * 8 + kb * 2 + 1]);
    }
#pragma unroll
    for (int ct = 0; ct < 2; ++ct) {
      int cc = wc * 32 + ct * 16 + lrow;
      fB[ct] = mk16(sW2[cc][kc2 * 8 + kb * 2], sW2[cc][kc2 * 8 + kb * 2 + 1]);
    }
#pragma unroll
    for (int ct = 0; ct < 2; ++ct)
#pragma unroll
      for (int rt = 0; rt < 4; ++rt)
        acc2[rt][ct] =
            __builtin_amdgcn_mfma_f32_16x16x32_f16(fA[rt], fB[ct], acc2[rt][ct], 0, 0, 0);
  }

#pragma unroll
  for (int ct = 0; ct < 2; ++ct) {
    int col = wc * 32 + ct * 16 + lrow;
    float bv = b2[col];
#pragma unroll
    for (int rt = 0; rt < 4; ++rt) {
#pragma unroll
      for (int r = 0; r < 4; ++r) {
        int g = row0 + wr * 64 + rt * 16 + kb * 4 + r;
        if (g < N_NODES) outp[(size_t)g * 64 + col] = acc2[rt][ct][r] + bv;
      }
    }
  }
}

// ---------------- launch ----------------

extern "C" void kernel_launch(void* const* d_in, const int* in_sizes, int n_in,
                              void* d_out, int out_size, void* d_ws, size_t ws_size,
                              hipStream_t stream) {
  const float* x = (const float*)d_in[0];
  const int* edge = (const int*)d_in[1];
  const int* src = edge;
  const int* dst = edge + N_EDGES;
  const float* Wl0 = (const float*)d_in[2];
  const float* bl0 = (const float*)d_in[3];
  const float* Wr0 = (const float*)d_in[4];
  const float* Wl1 = (const float*)d_in[5];
  const float* bl1 = (const float*)d_in[6];
  const float* Wr1 = (const float*)d_in[7];
  const float* Wl2 = (const float*)d_in[8];
  const float* bl2 = (const float*)d_in[9];
  const float* Wr2 = (const float*)d_in[10];
  const float* W = (const float*)d_in[11];
  const float* b = (const float*)d_in[12];
  float* out = (float*)d_out;
  (void)ws_size; (void)n_in; (void)in_sizes; (void)out_size;

  // workspace layout (high-water ~65.4 MB)
  char* ws = (char*)d_ws;
  float* sx = (float*)(ws);                                      // 400 KB
  float* sh = (float*)(ws + (512ll << 10));                      // 400 KB
  float* sa = (float*)(ws + (1ll << 20));                        // 400 KB
  int* row_start = (int*)(ws + (2ll << 20));                     // 400 KB
  int* row_end = (int*)(ws + (3ll << 20));                       // 400 KB
  float* inv_deg = (float*)(ws + (4ll << 20));                   // 400 KB
  int* csr_src = (int*)(ws + (5ll << 20));                       // 9.62 MB -> 14.62
  u32* offs = (u32*)(ws + (15ll << 20));                         // 3.14 MB -> 18.14
  unsigned short* wt16 = (unsigned short*)(ws + (19ll << 20));   // 213 KB
  unsigned char* agg8 = (unsigned char*)(ws + (20ll << 20));     // 12.8 MB -> 32.8
  unsigned char* x8 = (unsigned char*)(ws + (33ll << 20));       // 12.8 MB -> 45.8
  unsigned char* h8 = (unsigned char*)(ws + (46ll << 20));       // 12.8 MB -> 58.8
  u32* binned = (u32*)(ws + (59ll << 20));                       // 6.4 MB -> 65.4

  k_prep<<<NBLK + XBLK + WBLK, 256, 0, stream>>>(
      x, x8, sx, Wl0, Wr0, Wl1, Wr1, Wl2, Wr2, W, wt16, src, dst, binned, offs);
  k_build<<<NB, 256, 0, stream>>>(binned, offs, row_start, row_end, inv_deg, csr_src);

  const int agg_grid = (N_NODES + 31) / 32;
  const int gemm_grid = (N_NODES + 127) / 128;

  // layer 0: biased x8 in; biased agg out (signed means)
  k_agg<true, true><<<agg_grid, 256, 0, stream>>>(
      x8, sx, row_start, row_end, inv_deg, csr_src, agg8, sa);
  k_gemm<true, true><<<gemm_grid, 256, 0, stream>>>(
      agg8, sa, x8, sx, wt16 + 0, bl0, h8, sh);
  // layer 1: unsigned h8 in/out (relu'd)
  k_agg<false, false><<<agg_grid, 256, 0, stream>>>(
      h8, sh, row_start, row_end, inv_deg, csr_src, agg8, sa);
  k_gemm<false, false><<<gemm_grid, 256, 0, stream>>>(
      agg8, sa, h8, sh, wt16 + 32768, bl1, h8, sh);
  // layer 2 + fused final projection
  k_agg<false, false><<<agg_grid, 256, 0, stream>>>(
      h8, sh, row_start, row_end, inv_deg, csr_src, agg8, sa);
  k_gemm2<false, false><<<gemm_grid, 256, 0, stream>>>(
      agg8, sa, h8, sh, wt16 + 65536, bl2, wt16 + 98304, b, out);
}

// Round 15
// 244.771 us; speedup vs baseline: 1.0776x; 1.0776x over previous
//
#include <hip/hip_runtime.h>
#include <cstddef>

#define N_NODES 100000
#define N_EDGES 1600000
#define D 128
#define NB 782          // ceil(N_NODES/128) buckets of 128 dst nodes
#define CAP 3072        // csr/bucket window capacity (mean 2046, sd ~45)
#define NBLK 1000       // scatter blocks (CHUNK*NBLK == N_EDGES)
#define CHUNK 1600      // edges per scatter block
#define OROW 784        // offs row stride (NB+1 entries, padded)
#define WTOT (6 * 16384 + 8192)  // 106496 weight elements
#define XBLK 6250       // x-convert blocks
#define WBLK ((WTOT + 255) / 256)

typedef unsigned int u32;
typedef unsigned long long u64;
typedef float f32x4 __attribute__((ext_vector_type(4)));
typedef _Float16 f16x8 __attribute__((ext_vector_type(8)));

__device__ inline f16x8 mk16(u64 a, u64 b) {
  union { u64 q[2]; f16x8 v; } u;
  u.q[0] = a; u.q[1] = b;
  return u.v;
}

// accumulate 8 u8 lanes * scale into a[8]
__device__ inline void acc8(float* a, uint2 d, float c) {
  a[0] += (float)(d.x & 0xFFu) * c;
  a[1] += (float)((d.x >> 8) & 0xFFu) * c;
  a[2] += (float)((d.x >> 16) & 0xFFu) * c;
  a[3] += (float)(d.x >> 24) * c;
  a[4] += (float)(d.y & 0xFFu) * c;
  a[5] += (float)((d.y >> 8) & 0xFFu) * c;
  a[6] += (float)((d.y >> 16) & 0xFFu) * c;
  a[7] += (float)(d.y >> 24) * c;
}

// dequant 4 u8 -> 4 f16 (packed u64): val = q*c + n
__device__ inline u64 dq4(u32 w, float c, float n) {
  float f0 = fmaf((float)(w & 0xFFu), c, n);
  float f1 = fmaf((float)((w >> 8) & 0xFFu), c, n);
  float f2 = fmaf((float)((w >> 16) & 0xFFu), c, n);
  float f3 = fmaf((float)(w >> 24), c, n);
  auto lo = __builtin_amdgcn_cvt_pkrtz(f0, f1);  // __fp16 ext_vector(2)
  auto hi = __builtin_amdgcn_cvt_pkrtz(f2, f3);
  return (u64)__builtin_bit_cast(u32, lo) | ((u64)__builtin_bit_cast(u32, hi) << 32);
}

// ---------------- prep + scatter (merged: independent jobs, one launch) -------
// blocks [0,NBLK): edge scatter into private segments (R11-proven).
// blocks [NBLK, NBLK+XBLK): x -> biased-u8 + per-row scale.
// blocks [NBLK+XBLK, ...): weights -> transposed f16.

__global__ __launch_bounds__(256) void k_prep(
    const float* __restrict__ x,
    unsigned char* __restrict__ x8, float* __restrict__ sx,
    const float* __restrict__ w0, const float* __restrict__ w1, const float* __restrict__ w2,
    const float* __restrict__ w3, const float* __restrict__ w4, const float* __restrict__ w5,
    const float* __restrict__ w6, unsigned short* __restrict__ wt16,
    const int* __restrict__ src, const int* __restrict__ dst,
    u32* __restrict__ binned, u32* __restrict__ offs) {
  __shared__ int cnt[NB];
  __shared__ int lbase[NB + 1];
  __shared__ int wsum[256];
  __shared__ u32 stage[CHUNK];
  const int bid = blockIdx.x;
  const int tid = threadIdx.x;

  if (bid < NBLK) {
    // ---- scatter ----
    for (int i = tid; i < NB; i += 256) cnt[i] = 0;
    __syncthreads();
    const int e0 = bid * CHUNK;
    for (int e = e0 + tid; e < e0 + CHUNK; e += 256)
      atomicAdd(&cnt[dst[e] >> 7], 1);
    __syncthreads();
    int c[4], s = 0;
#pragma unroll
    for (int j = 0; j < 4; j++) {
      int i = tid * 4 + j;
      c[j] = (i < NB) ? cnt[i] : 0;
      s += c[j];
    }
    wsum[tid] = s;
    __syncthreads();
    for (int off = 1; off < 256; off <<= 1) {
      int t = (tid >= off) ? wsum[tid - off] : 0;
      __syncthreads();
      wsum[tid] += t;
      __syncthreads();
    }
    int run = wsum[tid] - s;
#pragma unroll
    for (int j = 0; j < 4; j++) {
      int i = tid * 4 + j;
      if (i < NB) { lbase[i] = run; run += c[j]; }
    }
    if (tid == 0) lbase[NB] = CHUNK;
    __syncthreads();
    for (int i = tid; i < NB; i += 256) cnt[i] = 0;
    __syncthreads();
    for (int e = e0 + tid; e < e0 + CHUNK; e += 256) {
      int d = dst[e];
      int bkt = d >> 7;
      int l = atomicAdd(&cnt[bkt], 1);
      stage[lbase[bkt] + l] = ((u32)(d & 127) << 17) | (u32)src[e];
    }
    u32* orow = offs + (size_t)bid * OROW;
    for (int i = tid; i <= NB; i += 256) orow[i] = (u32)lbase[i];
    __syncthreads();
    u32* bseg = binned + (size_t)bid * CHUNK;
    for (int i = tid; i < CHUNK / 4; i += 256)
      *(uint4*)(bseg + i * 4) = *(const uint4*)(stage + i * 4);
    return;
  }
  if (bid < NBLK + XBLK) {
    // ---- x convert ----
    int row = (bid - NBLK) * 16 + (tid >> 4);   // 6250*16 = 100000 exact
    int sub = tid & 15;
    const float* xr = x + (size_t)row * D + sub * 8;
    float4 v0 = *(const float4*)xr;
    float4 v1 = *(const float4*)(xr + 4);
    float vs[8] = {v0.x, v0.y, v0.z, v0.w, v1.x, v1.y, v1.z, v1.w};
    float m = 0.f;
#pragma unroll
    for (int j = 0; j < 8; j++) m = fmaxf(m, fabsf(vs[j]));
#pragma unroll
    for (int off = 1; off < 16; off <<= 1) m = fmaxf(m, __shfl_xor(m, off));
    m = fmaxf(m, 1e-8f);
    float inv = 127.0f / m;
    u64 pk = 0;
#pragma unroll
    for (int j = 0; j < 8; j++) {
      int qi = (int)rintf(vs[j] * inv) + 128;  // [1,255]
      pk |= (u64)(u32)(qi & 255) << (8 * j);
    }
    *(u64*)(x8 + (size_t)row * D + sub * 8) = pk;
    if (sub == 0) sx[row] = m / 127.0f;
    return;
  }
  // ---- weights ----
  int i = (bid - NBLK - XBLK) * 256 + tid;
  if (i >= WTOT) return;
  float v;
  if (i < 6 * 16384) {
    int m = i >> 14;  // 0..5 -> Wl0,Wr0,Wl1,Wr1,Wl2,Wr2
    int j = i & 16383;
    int c = j >> 7, k = j & 127;
    const float* w = (m == 0) ? w0 : (m == 1) ? w1 : (m == 2) ? w2
                   : (m == 3) ? w3 : (m == 4) ? w4 : w5;
    v = w[k * 128 + c];
  } else {
    int j = i - 6 * 16384;
    int c = j >> 7, k = j & 127;
    v = w6[k * 64 + c];
  }
  _Float16 h = (_Float16)v;
  wt16[i] = __builtin_bit_cast(unsigned short, h);
}

// ---------------- graph build, stage 2: per-bucket gather + CSR ----------------

__global__ __launch_bounds__(256) void k_build(const u32* __restrict__ binned,
                                               const u32* __restrict__ offs,
                                               int* __restrict__ row_start,
                                               int* __restrict__ row_end,
                                               float* __restrict__ inv_deg,
                                               int* __restrict__ csr_src) {
  __shared__ u32 stage[CAP];
  __shared__ int deg[128], sc[128], cur[128];
  __shared__ int fill;
  const int b = blockIdx.x;
  const int tid = threadIdx.x;
  if (tid == 0) fill = 0;
  if (tid < 128) deg[tid] = 0;
  __syncthreads();
  for (int k = tid; k < NBLK; k += 256) {
    const u32* orow = offs + (size_t)k * OROW;
    int o0 = (int)orow[b], o1 = (int)orow[b + 1];
    int n = o1 - o0;
    if (n > 0) {
      int p = atomicAdd(&fill, n);
      const u32* q = binned + (size_t)k * CHUNK + o0;
      for (int j = 0; j < n; ++j) stage[p + j] = q[j];
    }
  }
  __syncthreads();
  const int total = fill;
  for (int e = tid; e < total; e += 256)
    atomicAdd(&deg[stage[e] >> 17], 1);
  __syncthreads();
  int dv = (tid < 128) ? deg[tid] : 0;
  if (tid < 128) sc[tid] = dv;
  __syncthreads();
  for (int off = 1; off < 128; off <<= 1) {
    int t = (tid >= off && tid < 128) ? sc[tid - off] : 0;
    __syncthreads();
    if (tid < 128) sc[tid] += t;
    __syncthreads();
  }
  const int cbase = b * CAP;
  if (tid < 128) {
    int excl = sc[tid] - dv;
    cur[tid] = excl;
    int node = (b << 7) + tid;
    if (node < N_NODES) {
      row_start[node] = cbase + excl;
      row_end[node] = cbase + excl + dv;
      inv_deg[node] = 1.0f / fmaxf((float)dv, 1.0f);
    }
  }
  __syncthreads();
  for (int e = tid; e < total; e += 256) {
    u32 w = stage[e];
    int dl = w >> 17;
    int pos = cbase + atomicAdd(&cur[dl], 1);
    csr_src[pos] = (int)(w & 0x1FFFFu);
  }
}

// ---------------- aggregation: mean of neighbor u8 rows -> u8 + row scale ----
// R13-proven shape: 16 lanes/node, 8B/lane, unroll x8. BIN/BOUT as before.

template <bool BIN, bool BOUT>
__global__ __launch_bounds__(256) void k_agg(const unsigned char* __restrict__ q8,
                                             const float* __restrict__ qs,
                                             const int* __restrict__ row_start,
                                             const int* __restrict__ row_end,
                                             const float* __restrict__ inv_deg,
                                             const int* __restrict__ csr_src,
                                             unsigned char* __restrict__ out8,
                                             float* __restrict__ sout) {
  int node = blockIdx.x * 16 + (threadIdx.x >> 4);
  if (node >= N_NODES) return;
  int sub = threadIdx.x & 15;
  int p0 = row_start[node], p1 = row_end[node];
  float a[8];
#pragma unroll
  for (int j = 0; j < 8; j++) a[j] = 0.f;
  float ssum = 0.f;
  int p = p0;
  for (; p + 8 <= p1; p += 8) {
    int s0 = csr_src[p], s1 = csr_src[p + 1], s2 = csr_src[p + 2], s3 = csr_src[p + 3];
    int s4 = csr_src[p + 4], s5 = csr_src[p + 5], s6 = csr_src[p + 6], s7 = csr_src[p + 7];
    uint2 d0 = *(const uint2*)(q8 + (size_t)s0 * D + sub * 8);
    uint2 d1 = *(const uint2*)(q8 + (size_t)s1 * D + sub * 8);
    uint2 d2 = *(const uint2*)(q8 + (size_t)s2 * D + sub * 8);
    uint2 d3 = *(const uint2*)(q8 + (size_t)s3 * D + sub * 8);
    uint2 d4 = *(const uint2*)(q8 + (size_t)s4 * D + sub * 8);
    uint2 d5 = *(const uint2*)(q8 + (size_t)s5 * D + sub * 8);
    uint2 d6 = *(const uint2*)(q8 + (size_t)s6 * D + sub * 8);
    uint2 d7 = *(const uint2*)(q8 + (size_t)s7 * D + sub * 8);
    float c0 = qs[s0], c1 = qs[s1], c2 = qs[s2], c3 = qs[s3];
    float c4 = qs[s4], c5 = qs[s5], c6 = qs[s6], c7 = qs[s7];
    acc8(a, d0, c0); acc8(a, d1, c1); acc8(a, d2, c2); acc8(a, d3, c3);
    acc8(a, d4, c4); acc8(a, d5, c5); acc8(a, d6, c6); acc8(a, d7, c7);
    if (BIN) ssum += ((c0 + c1) + (c2 + c3)) + ((c4 + c5) + (c6 + c7));
  }
  for (; p + 2 <= p1; p += 2) {
    int s0 = csr_src[p], s1 = csr_src[p + 1];
    uint2 d0 = *(const uint2*)(q8 + (size_t)s0 * D + sub * 8);
    uint2 d1 = *(const uint2*)(q8 + (size_t)s1 * D + sub * 8);
    float c0 = qs[s0], c1 = qs[s1];
    acc8(a, d0, c0); acc8(a, d1, c1);
    if (BIN) ssum += c0 + c1;
  }
  if (p < p1) {
    int s0 = csr_src[p];
    uint2 d0 = *(const uint2*)(q8 + (size_t)s0 * D + sub * 8);
    float c0 = qs[s0];
    acc8(a, d0, c0);
    if (BIN) ssum += c0;
  }
  float scl = inv_deg[node];
  float v[8];
#pragma unroll
  for (int j = 0; j < 8; j++) {
    float t = a[j];
    if (BIN) t -= 128.0f * ssum;
    v[j] = t * scl;
  }
  float m = 0.f;
#pragma unroll
  for (int j = 0; j < 8; j++) m = fmaxf(m, BOUT ? fabsf(v[j]) : v[j]);
#pragma unroll
  for (int off = 1; off < 16; off <<= 1) m = fmaxf(m, __shfl_xor(m, off));
  m = fmaxf(m, 1e-8f);
  u64 pk = 0;
  if (BOUT) {
    float inv = 127.0f / m;
#pragma unroll
    for (int j = 0; j < 8; j++) {
      int qi = (int)rintf(v[j] * inv) + 128;
      pk |= (u64)(u32)(qi & 255) << (8 * j);
    }
  } else {
    float inv = 255.0f / m;
#pragma unroll
    for (int j = 0; j < 8; j++) {
      u32 qi = (u32)(v[j] * inv + 0.5f);
      pk |= (u64)(qi & 255) << (8 * j);
    }
  }
  *(u64*)(out8 + (size_t)node * D + sub * 8) = pk;
  if (sub == 0) sout[node] = m / (BOUT ? 127.0f : 255.0f);
}

// ---------------- MFMA GEMM (layers 0,1): all-u8 operands, dequant in staging ----

template <bool B0, bool B1>
__global__ __launch_bounds__(256) void k_gemm(
    const unsigned char* __restrict__ in0, const float* __restrict__ s0,
    const unsigned char* __restrict__ in1, const float* __restrict__ s1,
    const unsigned short* __restrict__ wt, const float* __restrict__ bias,
    unsigned char* __restrict__ h8out, float* __restrict__ shout) {
  __shared__ u64 sI[128][9];
  __shared__ u64 sW[128][9];
  __shared__ u32 rmaxb[128];
  __shared__ unsigned char h8t[128 * 144];  // stride 144 (16B-aligned rows)

  const int tid = threadIdx.x;
  const int row0 = blockIdx.x * 128;
  const int lane = tid & 63;
  const int w = tid >> 6;
  const int wr = w >> 1, wc = w & 1;
  const int lrow = lane & 15, kb = lane >> 4;
  const int sr = tid >> 2, sq = tid & 3;

  f32x4 acc[4][4];
#pragma unroll
  for (int i = 0; i < 4; i++)
#pragma unroll
    for (int j = 0; j < 4; j++) acc[i][j] = (f32x4){0.f, 0.f, 0.f, 0.f};

  uint2 rd[2]; float rc[2];
  u64 rW[2][2];

  auto loadA = [&](int ch) {
    const unsigned char* inP = (ch >= 4) ? in1 : in0;
    const float* sP = (ch >= 4) ? s1 : s0;
    const int kc = (ch & 3) * 32;
#pragma unroll
    for (int it = 0; it < 2; ++it) {
      int g = row0 + sr + it * 64;
      uint2 d = make_uint2(0, 0);
      float c = 0.f;
      if (g < N_NODES) {
        d = *(const uint2*)(inP + (size_t)g * D + kc + sq * 8);
        c = sP[g];
      }
      rd[it] = d; rc[it] = c;
    }
  };
  auto loadW = [&](int ch) {
    const int s = ch >> 2;
    const int kc = (ch & 3) * 32;
    const unsigned short* wP = wt + (size_t)s * 16384;
#pragma unroll
    for (int it = 0; it < 2; ++it) {
      int c = sr + it * 64;
      const u64* pp = (const u64*)(wP + (size_t)c * D + kc + sq * 8);
      rW[it][0] = pp[0]; rW[it][1] = pp[1];
    }
  };

  loadA(0); loadW(0);
#pragma unroll
  for (int ch = 0; ch < 8; ++ch) {
    const bool biased = (ch < 4) ? B0 : B1;
    __syncthreads();
#pragma unroll
    for (int it = 0; it < 2; ++it) {
      int r = sr + it * 64;
      float c = rc[it];
      float n = biased ? -128.0f * c : 0.0f;
      sI[r][sq * 2] = dq4(rd[it].x, c, n);
      sI[r][sq * 2 + 1] = dq4(rd[it].y, c, n);
      sW[r][sq * 2] = rW[it][0]; sW[r][sq * 2 + 1] = rW[it][1];
    }
    __syncthreads();
    if (ch < 7) { loadA(ch + 1); loadW(ch + 1); }

    f16x8 fA[4], fB[4];
#pragma unroll
    for (int rt = 0; rt < 4; ++rt) {
      int rr = wr * 64 + rt * 16 + lrow;
      fA[rt] = mk16(sI[rr][kb * 2], sI[rr][kb * 2 + 1]);
    }
#pragma unroll
    for (int ct = 0; ct < 4; ++ct) {
      int cc = wc * 64 + ct * 16 + lrow;
      fB[ct] = mk16(sW[cc][kb * 2], sW[cc][kb * 2 + 1]);
    }
#pragma unroll
    for (int ct = 0; ct < 4; ++ct)
#pragma unroll
      for (int rt = 0; rt < 4; ++rt)
        acc[rt][ct] = __builtin_amdgcn_mfma_f32_16x16x32_f16(fA[rt], fB[ct], acc[rt][ct], 0, 0, 0);
  }

  // ---- epilogue: bias+relu, rowmax, u8 quantize ----
  if (tid < 128) rmaxb[tid] = 0;
  float bv[4];
#pragma unroll
  for (int ct = 0; ct < 4; ++ct) bv[ct] = bias[wc * 64 + ct * 16 + lrow];
#pragma unroll
  for (int ct = 0; ct < 4; ++ct)
#pragma unroll
    for (int rt = 0; rt < 4; ++rt)
#pragma unroll
      for (int r = 0; r < 4; ++r)
        acc[rt][ct][r] = fmaxf(acc[rt][ct][r] + bv[ct], 0.f);
  __syncthreads();  // rmaxb init visible
#pragma unroll
  for (int rt = 0; rt < 4; ++rt) {
#pragma unroll
    for (int r = 0; r < 4; ++r) {
      float m = fmaxf(fmaxf(acc[rt][0][r], acc[rt][1][r]),
                      fmaxf(acc[rt][2][r], acc[rt][3][r]));
      m = fmaxf(m, __shfl_xor(m, 1));
      m = fmaxf(m, __shfl_xor(m, 2));
      m = fmaxf(m, __shfl_xor(m, 4));
      m = fmaxf(m, __shfl_xor(m, 8));
      if (lrow == 0)
        atomicMax(&rmaxb[wr * 64 + rt * 16 + kb * 4 + r], __float_as_uint(m));
    }
  }
  __syncthreads();
#pragma unroll
  for (int rt = 0; rt < 4; ++rt) {
#pragma unroll
    for (int r = 0; r < 4; ++r) {
      int row = wr * 64 + rt * 16 + kb * 4 + r;
      float rm = fmaxf(__uint_as_float(rmaxb[row]), 1e-8f);
      float inv = 255.0f / rm;
#pragma unroll
      for (int ct = 0; ct < 4; ++ct) {
        u32 q = (u32)(acc[rt][ct][r] * inv + 0.5f);
        h8t[row * 144 + wc * 64 + ct * 16 + lrow] = (unsigned char)q;
      }
    }
  }
  __syncthreads();
  for (int idx = tid; idx < 128 * 8; idx += 256) {
    int row = idx >> 3, qq = idx & 7;
    int g = row0 + row;
    if (g < N_NODES)
      *(uint4*)(h8out + (size_t)g * D + qq * 16) =
          *(const uint4*)(h8t + row * 144 + qq * 16);
  }
  if (tid < 128 && row0 + tid < N_NODES)
    shout[row0 + tid] = fmaxf(__uint_as_float(rmaxb[tid]), 1e-8f) / 255.0f;
}

// ---------------- layer-2 GEMM + fused final projection (u8 operands) ----------

template <bool B0, bool B1>
__global__ __launch_bounds__(256) void k_gemm2(
    const unsigned char* __restrict__ in0, const float* __restrict__ s0,
    const unsigned char* __restrict__ in1, const float* __restrict__ s1,
    const unsigned short* __restrict__ wt, const float* __restrict__ bias,
    const unsigned short* __restrict__ w2, const float* __restrict__ b2,
    float* __restrict__ outp) {
  __shared__ __align__(16) char smem[128 * 33 * 8 + 2 * 128 * 9 * 8];
  u64 (*sH3)[33] = (u64(*)[33])smem;
  u64 (*sI)[9] = (u64(*)[9])(smem + 128 * 33 * 8);
  u64 (*sW)[9] = (u64(*)[9])(smem + 128 * 33 * 8 + 128 * 9 * 8);
  u64 (*sW2)[33] = (u64(*)[33])(smem + 128 * 33 * 8);  // alias of sI/sW, phase B only

  const int tid = threadIdx.x;
  const int row0 = blockIdx.x * 128;
  const int lane = tid & 63;
  const int w = tid >> 6;
  const int wr = w >> 1, wc = w & 1;
  const int lrow = lane & 15, kb = lane >> 4;
  const int sr = tid >> 2, sq = tid & 3;

  f32x4 acc[4][4];
#pragma unroll
  for (int i = 0; i < 4; i++)
#pragma unroll
    for (int j = 0; j < 4; j++) acc[i][j] = (f32x4){0.f, 0.f, 0.f, 0.f};

  uint2 rd[2]; float rc[2];
  u64 rW[2][2];

  auto loadA = [&](int ch) {
    const unsigned char* inP = (ch >= 4) ? in1 : in0;
    const float* sP = (ch >= 4) ? s1 : s0;
    const int kc = (ch & 3) * 32;
#pragma unroll
    for (int it = 0; it < 2; ++it) {
      int g = row0 + sr + it * 64;
      uint2 d = make_uint2(0, 0);
      float c = 0.f;
      if (g < N_NODES) {
        d = *(const uint2*)(inP + (size_t)g * D + kc + sq * 8);
        c = sP[g];
      }
      rd[it] = d; rc[it] = c;
    }
  };
  auto loadW = [&](int ch) {
    const int s = ch >> 2;
    const int kc = (ch & 3) * 32;
    const unsigned short* wP = wt + (size_t)s * 16384;
#pragma unroll
    for (int it = 0; it < 2; ++it) {
      int c = sr + it * 64;
      const u64* pp = (const u64*)(wP + (size_t)c * D + kc + sq * 8);
      rW[it][0] = pp[0]; rW[it][1] = pp[1];
    }
  };

  loadA(0); loadW(0);
#pragma unroll
  for (int ch = 0; ch < 8; ++ch) {
    const bool biased = (ch < 4) ? B0 : B1;
    __syncthreads();
#pragma unroll
    for (int it = 0; it < 2; ++it) {
      int r = sr + it * 64;
      float c = rc[it];
      float n = biased ? -128.0f * c : 0.0f;
      sI[r][sq * 2] = dq4(rd[it].x, c, n);
      sI[r][sq * 2 + 1] = dq4(rd[it].y, c, n);
      sW[r][sq * 2] = rW[it][0]; sW[r][sq * 2 + 1] = rW[it][1];
    }
    __syncthreads();
    if (ch < 7) { loadA(ch + 1); loadW(ch + 1); }

    f16x8 fA[4], fB[4];
#pragma unroll
    for (int rt = 0; rt < 4; ++rt) {
      int rr = wr * 64 + rt * 16 + lrow;
      fA[rt] = mk16(sI[rr][kb * 2], sI[rr][kb * 2 + 1]);
    }
#pragma unroll
    for (int ct = 0; ct < 4; ++ct) {
      int cc = wc * 64 + ct * 16 + lrow;
      fB[ct] = mk16(sW[cc][kb * 2], sW[cc][kb * 2 + 1]);
    }
#pragma unroll
    for (int ct = 0; ct < 4; ++ct)
#pragma unroll
      for (int rt = 0; rt < 4; ++rt)
        acc[rt][ct] = __builtin_amdgcn_mfma_f32_16x16x32_f16(fA[rt], fB[ct], acc[rt][ct], 0, 0, 0);
  }

  // ---- phase B ----
#pragma unroll
  for (int ct = 0; ct < 4; ++ct) {
    int col = wc * 64 + ct * 16 + lrow;
    float bv = bias[col];
#pragma unroll
    for (int rt = 0; rt < 4; ++rt) {
      int rbase = wr * 64 + rt * 16 + kb * 4;
#pragma unroll
      for (int r = 0; r < 4; ++r) {
        float v = fmaxf(acc[rt][ct][r] + bv, 0.f);
        _Float16 hv = (_Float16)v;
        ((unsigned short*)(&sH3[rbase + r][0]))[col] = __builtin_bit_cast(unsigned short, hv);
      }
    }
  }
  __syncthreads();  // phase-A LDS reads retired; h3 visible -> safe to alias sI/sW
  for (int idx = tid; idx < 64 * 32; idx += 256) {
    int c = idx >> 5, j = idx & 31;
    sW2[c][j] = ((const u64*)(w2 + (size_t)c * D))[j];
  }
  __syncthreads();

  f32x4 acc2[4][2];
#pragma unroll
  for (int i = 0; i < 4; i++)
#pragma unroll
    for (int j = 0; j < 2; j++) acc2[i][j] = (f32x4){0.f, 0.f, 0.f, 0.f};

#pragma unroll
  for (int kc2 = 0; kc2 < 4; ++kc2) {
    f16x8 fA[4], fB[2];
#pragma unroll
    for (int rt = 0; rt < 4; ++rt) {
      int rr = wr * 64 + rt * 16 + lrow;
      fA[rt] = mk16(sH3[rr][kc2 * 8 + kb * 2], sH3[rr][kc2 * 8 + kb * 2 + 1]);
    }
#pragma unroll
    for (int ct = 0; ct < 2; ++ct) {
      int cc = wc * 32 + ct * 16 + lrow;
      fB[ct] = mk16(sW2[cc][kc2 * 8 + kb * 2], sW2[cc][kc2 * 8 + kb * 2 + 1]);
    }
#pragma unroll
    for (int ct = 0; ct < 2; ++ct)
#pragma unroll
      for (int rt = 0; rt < 4; ++rt)
        acc2[rt][ct] =
            __builtin_amdgcn_mfma_f32_16x16x32_f16(fA[rt], fB[ct], acc2[rt][ct], 0, 0, 0);
  }

#pragma unroll
  for (int ct = 0; ct < 2; ++ct) {
    int col = wc * 32 + ct * 16 + lrow;
    float bv = b2[col];
#pragma unroll
    for (int rt = 0; rt < 4; ++rt) {
#pragma unroll
      for (int r = 0; r < 4; ++r) {
        int g = row0 + wr * 64 + rt * 16 + kb * 4 + r;
        if (g < N_NODES) outp[(size_t)g * 64 + col] = acc2[rt][ct][r] + bv;
      }
    }
  }
}

// ---------------- launch ----------------

extern "C" void kernel_launch(void* const* d_in, const int* in_sizes, int n_in,
                              void* d_out, int out_size, void* d_ws, size_t ws_size,
                              hipStream_t stream) {
  const float* x = (const float*)d_in[0];
  const int* edge = (const int*)d_in[1];
  const int* src = edge;
  const int* dst = edge + N_EDGES;
  const float* Wl0 = (const float*)d_in[2];
  const float* bl0 = (const float*)d_in[3];
  const float* Wr0 = (const float*)d_in[4];
  const float* Wl1 = (const float*)d_in[5];
  const float* bl1 = (const float*)d_in[6];
  const float* Wr1 = (const float*)d_in[7];
  const float* Wl2 = (const float*)d_in[8];
  const float* bl2 = (const float*)d_in[9];
  const float* Wr2 = (const float*)d_in[10];
  const float* W = (const float*)d_in[11];
  const float* b = (const float*)d_in[12];
  float* out = (float*)d_out;
  (void)ws_size; (void)n_in; (void)in_sizes; (void)out_size;

  // workspace layout (high-water ~65.4 MB)
  char* ws = (char*)d_ws;
  float* sx = (float*)(ws);                                      // 400 KB
  float* sh = (float*)(ws + (512ll << 10));                      // 400 KB
  float* sa = (float*)(ws + (1ll << 20));                        // 400 KB
  int* row_start = (int*)(ws + (2ll << 20));                     // 400 KB
  int* row_end = (int*)(ws + (3ll << 20));                       // 400 KB
  float* inv_deg = (float*)(ws + (4ll << 20));                   // 400 KB
  int* csr_src = (int*)(ws + (5ll << 20));                       // 9.62 MB -> 14.62
  u32* offs = (u32*)(ws + (15ll << 20));                         // 3.14 MB -> 18.14
  unsigned short* wt16 = (unsigned short*)(ws + (19ll << 20));   // 213 KB
  unsigned char* agg8 = (unsigned char*)(ws + (20ll << 20));     // 12.8 MB -> 32.8
  unsigned char* x8 = (unsigned char*)(ws + (33ll << 20));       // 12.8 MB -> 45.8
  unsigned char* h8 = (unsigned char*)(ws + (46ll << 20));       // 12.8 MB -> 58.8
  u32* binned = (u32*)(ws + (59ll << 20));                       // 6.4 MB -> 65.4

  k_prep<<<NBLK + XBLK + WBLK, 256, 0, stream>>>(
      x, x8, sx, Wl0, Wr0, Wl1, Wr1, Wl2, Wr2, W, wt16, src, dst, binned, offs);
  k_build<<<NB, 256, 0, stream>>>(binned, offs, row_start, row_end, inv_deg, csr_src);

  const int agg_grid = (N_NODES + 15) / 16;
  const int gemm_grid = (N_NODES + 127) / 128;

  // layer 0: biased x8 in; biased agg out (signed means)
  k_agg<true, true><<<agg_grid, 256, 0, stream>>>(
      x8, sx, row_start, row_end, inv_deg, csr_src, agg8, sa);
  k_gemm<true, true><<<gemm_grid, 256, 0, stream>>>(
      agg8, sa, x8, sx, wt16 + 0, bl0, h8, sh);
  // layer 1: unsigned h8 in/out (relu'd)
  k_agg<false, false><<<agg_grid, 256, 0, stream>>>(
      h8, sh, row_start, row_end, inv_deg, csr_src, agg8, sa);
  k_gemm<false, false><<<gemm_grid, 256, 0, stream>>>(
      agg8, sa, h8, sh, wt16 + 32768, bl1, h8, sh);
  // layer 2 + fused final projection
  k_agg<false, false><<<agg_grid, 256, 0, stream>>>(
      h8, sh, row_start, row_end, inv_deg, csr_src, agg8, sa);
  k_gemm2<false, false><<<gemm_grid, 256, 0, stream>>>(
      agg8, sa, h8, sh, wt16 + 65536, bl2, wt16 + 98304, b, out);
}